// Round 6
// baseline (830.089 us; speedup 1.0000x reference)
//
#include <hip/hip_runtime.h>

#define N_ENTITIES 200000
#define N_ITEMS    100000
#define DIM        64
#define N_EDGES    1500000
#define K_EDGES    256
#define K_ITEMS    100
// 1 / (2 * sqrt(32))  (mean over 2 heads of per-head 1/sqrt(Dk))
#define SCALE      0.08838834764831845f

#define CAND_CAP   4096

typedef unsigned long long u64;

// ---- monotonic float<->u32 key (order-preserving, total order) ----
__device__ __forceinline__ unsigned fkey(float x) {
    unsigned u = __float_as_uint(x);
    return (u & 0x80000000u) ? ~u : (u | 0x80000000u);
}
__device__ __forceinline__ float funkey(unsigned k) {
    return (k & 0x80000000u) ? __uint_as_float(k & 0x7fffffffu)
                             : __uint_as_float(~k);
}

// wave-aggregated LDS histogram add: one LDS atomic per distinct bin per wave
__device__ __forceinline__ void lds_hist_add(unsigned* h, unsigned bin, bool valid, int lane) {
    bool need = valid;
    for (;;) {
        unsigned long long mask = __ballot(need);
        if (mask == 0ull) break;
        int leader = __ffsll(mask) - 1;
        unsigned lbin = __shfl(bin, leader, 64);
        bool same = need && (bin == lbin);
        unsigned long long grp = __ballot(same);
        if (lane == leader) atomicAdd(&h[lbin], (unsigned)__popcll(grp));
        need = need && !same;
    }
}

// serial 256-bin select: largest bin b with count(>b) < Keff <= count(>=b).
__device__ __forceinline__ unsigned select_digit(const unsigned* __restrict__ hist,
                                                 unsigned Keff, unsigned* above) {
    unsigned cum = 0;
    int b = 255;
    for (; b > 0; --b) {
        unsigned hb = hist[b];
        if (cum + hb >= Keff) break;
        cum += hb;
    }
    *above = cum;
    return (unsigned)b;
}

// ---- proj = emb @ W_Q, fused with head-degree histogram WITH returned rank
// (the atomic round-trip hides behind the GEMM). 256 thr = (q x c); 16 rows/blk.
__global__ __launch_bounds__(256) void proj_kernel(const float* __restrict__ emb,
                                                   const float* __restrict__ W,
                                                   float* __restrict__ proj,
                                                   const int* __restrict__ head,
                                                   unsigned* __restrict__ degi,
                                                   unsigned* __restrict__ rank) {
    // fused: degree histogram + rank capture (grid 12500*256 = 3.2M >= N_EDGES)
    int e = blockIdx.x * blockDim.x + threadIdx.x;
    if (e < N_EDGES) rank[e] = atomicAdd(&degi[head[e]], 1u);

    __shared__ float part[4][16][64];
    const int t = threadIdx.x;
    const int c = t & 63;
    const int q = __builtin_amdgcn_readfirstlane(t >> 6);

    float Wreg[16];
#pragma unroll
    for (int j = 0; j < 16; ++j) Wreg[j] = W[(q * 16 + j) * 64 + c];

    const int base = blockIdx.x * 16;   // 200000 = 12500 * 16, exact
    const float* erow = emb + (size_t)base * 64 + q * 16;

    float acc[16];
#pragma unroll
    for (int r = 0; r < 16; ++r) acc[r] = 0.f;
#pragma unroll
    for (int r = 0; r < 16; ++r) {
#pragma unroll
        for (int j = 0; j < 16; ++j)
            acc[r] += erow[r * 64 + j] * Wreg[j];
    }
#pragma unroll
    for (int r = 0; r < 16; ++r) part[q][r][c] = acc[r];
    __syncthreads();
#pragma unroll
    for (int it = 0; it < 4; ++it) {
        int oi = t + it * 256;
        int r = oi >> 6, cc = oi & 63;
        float s = part[0][r][cc] + part[1][r][cc] + part[2][r][cc] + part[3][r][cc];
        proj[(size_t)(base + r) * 64 + cc] = s;
    }
}

// ---- single-block exclusive scan of degi -> start (chunked, 1024 threads) ----
__global__ __launch_bounds__(1024) void scan_kernel(const unsigned* __restrict__ degi,
                                                    unsigned* __restrict__ start) {
    __shared__ unsigned bs[1024];
    const int CH = (N_ENTITIES + 1023) / 1024;   // 196
    int t = threadIdx.x;
    int lo = t * CH, hi = lo + CH;
    if (hi > N_ENTITIES) hi = N_ENTITIES;
    unsigned s = 0;
    for (int i = lo; i < hi; ++i) s += degi[i];
    bs[t] = s;
    __syncthreads();
    for (int off = 1; off < 1024; off <<= 1) {
        unsigned v = bs[t];
        unsigned w = (t >= off) ? bs[t - off] : 0u;
        __syncthreads();
        bs[t] = v + w;
        __syncthreads();
    }
    unsigned run = bs[t] - s;   // exclusive prefix of this chunk
    for (int i = lo; i < hi; ++i) {
        unsigned d = degi[i];
        start[i] = run;
        run += d;
    }
}

// ---- atomic-free scatter: slot = start[head] + rank ----
// rec = tail(18b)<<27 | rel(6b)<<21 | eid(21b)
__global__ void scatter_kernel(const int* __restrict__ head, const int* __restrict__ tail,
                               const int* __restrict__ etype,
                               const unsigned* __restrict__ rank,
                               const unsigned* __restrict__ start,
                               u64* __restrict__ rec) {
    int i = blockIdx.x * blockDim.x + threadIdx.x;
    if (i >= N_EDGES) return;
    unsigned slot = start[head[i]] + rank[i];
    u64 R = ((u64)(unsigned)tail[i] << 27) | ((u64)(unsigned)(etype[i] - 1) << 21) | (u64)(unsigned)i;
    rec[slot] = R;
}

// ---- CSR main pass: one wave per head node, 4 edges per iteration ----
// denom/deg/sum_head in-register (NO atomics); only sumtail[tail<N_ITEMS] atomic.
__global__ __launch_bounds__(256) void node_pass(const float4* __restrict__ proj4,
                                                 const float4* __restrict__ rel4,
                                                 const u64* __restrict__ rec,
                                                 const unsigned* __restrict__ start,
                                                 const unsigned* __restrict__ degi,
                                                 float* __restrict__ logits,
                                                 float2* __restrict__ nd,
                                                 float* __restrict__ sumhead,
                                                 float* __restrict__ sumtail) {
    int wave = (blockIdx.x * blockDim.x + threadIdx.x) >> 6;   // node id (grid exact)
    int lane = threadIdx.x & 63;
    int slot = lane >> 4, sl = lane & 15;
    unsigned s = start[wave], len = degi[wave];
    float4 ph = proj4[(size_t)wave * 16 + sl];
    float dsum = 0.f, lsum = 0.f;
    for (unsigned k0 = 0; k0 < len; k0 += 4) {
        unsigned k = k0 + slot;
        bool valid = (k < len);
        u64 R = rec[s + (valid ? k : 0u)];
        unsigned t = (unsigned)(R >> 27);
        unsigned r = ((unsigned)(R >> 21)) & 63u;
        unsigned eid = (unsigned)R & 0x1FFFFFu;
        float4 pt = proj4[(size_t)t * 16 + sl];
        float4 pr = rel4[(size_t)r * 16 + sl];
        float v = ph.x * pt.x * pr.x + ph.y * pt.y * pr.y + ph.z * pt.z * pr.z + ph.w * pt.w * pr.w;
        v += __shfl_xor(v, 1, 64);
        v += __shfl_xor(v, 2, 64);
        v += __shfl_xor(v, 4, 64);
        v += __shfl_xor(v, 8, 64);
        if (sl == 0 && valid) {
            float lg = v * SCALE;
            logits[eid] = lg;
            dsum += __expf(lg);
            lsum += lg;
            if (t < N_ITEMS) atomicAdd(&sumtail[t], lg);
        }
    }
    dsum += __shfl_xor(dsum, 16, 64);
    dsum += __shfl_xor(dsum, 32, 64);
    lsum += __shfl_xor(lsum, 16, 64);
    lsum += __shfl_xor(lsum, 32, 64);
    if (lane == 0) {
        nd[wave] = make_float2(dsum, (float)len);
        sumhead[wave] = lsum;
    }
}

// ---- item keys (sumhead + sumtail) + item stage-0 histogram ----
__global__ void reduce_items(const float* __restrict__ a, const float* __restrict__ b,
                             unsigned* __restrict__ keysI, unsigned* __restrict__ histA_I) {
    __shared__ unsigned h[256];
    for (int j = threadIdx.x; j < 256; j += blockDim.x) h[j] = 0;
    __syncthreads();
    int i = blockIdx.x * blockDim.x + threadIdx.x;
    int lane = threadIdx.x & 63;
    unsigned bin = 0;
    bool valid = (i < N_ITEMS);
    if (valid) {
        float s = a[i] + b[i];
        unsigned k = fkey(s);
        keysI[i] = k;
        bin = k >> 24;
    }
    lds_hist_add(h, bin, valid, lane);
    __syncthreads();
    for (int j = threadIdx.x; j < 256; j += blockDim.x) {
        unsigned v = h[j];
        if (v) atomicAdd(&histA_I[j], v);
    }
}

// ---- scores + gumbel keys + edge stage-0 histogram ----
__global__ void edge_pass3(const float* __restrict__ logits, const int* __restrict__ head,
                           const float2* __restrict__ nd, const float* __restrict__ noise_u,
                           float* __restrict__ out_scores, unsigned* __restrict__ keysE,
                           unsigned* __restrict__ histA_E) {
    __shared__ unsigned h[256];
    for (int j = threadIdx.x; j < 256; j += blockDim.x) h[j] = 0;
    __syncthreads();
    int i = blockIdx.x * blockDim.x + threadIdx.x;
    int lane = threadIdx.x & 63;
    unsigned bin = 0;
    bool valid = (i < N_EDGES);
    if (valid) {
        float lg = logits[i];
        float2 dd = nd[head[i]];
        float score = __expf(lg) / dd.x * dd.y;
        out_scores[i] = score;
        float noise = -logf(-logf(noise_u[i]));
        unsigned k = fkey(score + noise);
        keysE[i] = k;
        bin = k >> 24;
    }
    lds_hist_add(h, bin, valid, lane);
    __syncthreads();
    for (int j = threadIdx.x; j < 256; j += blockDim.x) {
        unsigned v = h[j];
        if (v) atomicAdd(&histA_E[j], v);
    }
}

// ---- radix stages 1,2 (grid.y: 0=edges, 1=items); hists [y][stage][256] ----
__global__ void hist_stage_kernel(const unsigned* __restrict__ keysE,
                                  const unsigned* __restrict__ keysI,
                                  unsigned* __restrict__ hists, int stage) {
    __shared__ unsigned h[256];
    for (int j = threadIdx.x; j < 256; j += blockDim.x) h[j] = 0;
    __syncthreads();
    const int y = blockIdx.y;
    const unsigned* keys = y ? keysI : keysE;
    const int n = y ? N_ITEMS : N_EDGES;
    const unsigned K = y ? K_ITEMS : K_EDGES;
    unsigned* H = hists + (size_t)y * 3 * 256;

    unsigned aboveA, prefix;
    unsigned binA = select_digit(H, K, &aboveA);
    if (stage == 1) {
        prefix = binA;
    } else {
        unsigned aboveB;
        unsigned binB = select_digit(H + 256, K - aboveA, &aboveB);
        prefix = (binA << 8) | binB;
    }
    const int shift = 24 - 8 * stage;
    unsigned* out = H + stage * 256;

    const int lane = threadIdx.x & 63;
    const int stride = gridDim.x * blockDim.x;
    for (int idx = blockIdx.x * blockDim.x + threadIdx.x; idx - lane < n; idx += stride) {
        bool valid = (idx < n);
        unsigned bin = 0;
        if (valid) {
            unsigned k = keys[idx];
            if ((k >> (shift + 8)) != prefix) valid = false;
            bin = (k >> shift) & 0xFFu;
        }
        lds_hist_add(h, bin, valid, lane);
    }
    __syncthreads();
    for (int j = threadIdx.x; j < 256; j += blockDim.x) {
        unsigned v = h[j];
        if (v) atomicAdd(&out[j], v);
    }
}

// ---- collect candidates >= 24-bit threshold ----
__global__ void collect_kernel(const unsigned* __restrict__ keysE,
                               const unsigned* __restrict__ keysI,
                               const unsigned* __restrict__ hists,
                               unsigned* __restrict__ counters, unsigned* __restrict__ cand) {
    const int y = blockIdx.y;
    const unsigned* keys = y ? keysI : keysE;
    const int n = y ? N_ITEMS : N_EDGES;
    const unsigned K = y ? K_ITEMS : K_EDGES;
    const unsigned* H = hists + (size_t)y * 3 * 256;
    unsigned aboveA, aboveB, aboveC;
    unsigned binA = select_digit(H, K, &aboveA);
    unsigned binB = select_digit(H + 256, K - aboveA, &aboveB);
    unsigned binC = select_digit(H + 512, K - aboveA - aboveB, &aboveC);
    const unsigned T = ((binA << 16) | (binB << 8) | binC) << 8;
    unsigned* cd = cand + (size_t)y * 2 * CAND_CAP;

    int i = blockIdx.x * blockDim.x + threadIdx.x;
    int stride = gridDim.x * blockDim.x;
    for (; i < n; i += stride) {
        unsigned k = keys[i];
        if (k >= T) {
            unsigned p = atomicAdd(&counters[y], 1u);
            if (p < (unsigned)CAND_CAP) { cd[2 * p] = k; cd[2 * p + 1] = (unsigned)i; }
        }
    }
}

// ---- exact rank among candidates (key desc, index asc); 2 blocks (y) ----
__global__ void final_topk_kernel(const unsigned* __restrict__ cand,
                                  const unsigned* __restrict__ counters,
                                  float* __restrict__ out_topkv, float* __restrict__ out_topki,
                                  float* __restrict__ out_itemv, float* __restrict__ out_itemi) {
    __shared__ unsigned sk[CAND_CAP];
    __shared__ unsigned si[CAND_CAP];
    const int y = blockIdx.x;
    const int K = y ? K_ITEMS : K_EDGES;
    float* outv = y ? out_itemv : out_topkv;
    float* outi = y ? out_itemi : out_topki;
    const unsigned* cd = cand + (size_t)y * 2 * CAND_CAP;
    unsigned m = counters[y];
    if (m > (unsigned)CAND_CAP) m = CAND_CAP;
    for (unsigned i = threadIdx.x; i < m; i += blockDim.x) {
        sk[i] = cd[2 * i];
        si[i] = cd[2 * i + 1];
    }
    __syncthreads();
    for (unsigned i = threadIdx.x; i < m; i += blockDim.x) {
        unsigned ki = sk[i], xi = si[i];
        int r = 0;
        for (unsigned j = 0; j < m; ++j) {
            unsigned kj = sk[j];
            if (kj > ki || (kj == ki && si[j] < xi)) r++;
        }
        if (r < K) {
            outv[r] = funkey(ki);
            outi[r] = (float)xi;
        }
    }
}

extern "C" void kernel_launch(void* const* d_in, const int* in_sizes, int n_in,
                              void* d_out, int out_size, void* d_ws, size_t ws_size,
                              hipStream_t stream) {
    (void)in_sizes; (void)n_in; (void)out_size; (void)ws_size;
    const float* emb    = (const float*)d_in[0];
    const float* W      = (const float*)d_in[1];
    const float* rel    = (const float*)d_in[2];
    const float* noise  = (const float*)d_in[3];
    const int*   eidx   = (const int*)d_in[4];
    const int*   etype  = (const int*)d_in[5];
    const int* head = eidx;
    const int* tail = eidx + N_EDGES;

    float* out        = (float*)d_out;
    float* out_scores = out;
    float* out_topkv  = out + N_EDGES;
    float* out_topki  = out + N_EDGES + K_EDGES;
    float* out_itemv  = out + N_EDGES + 2 * K_EDGES;
    float* out_itemi  = out + N_EDGES + 2 * K_EDGES + K_ITEMS;

    float* ws = (float*)d_ws;
    size_t o = 0;
    float*    proj    = ws + o;               o += (size_t)N_ENTITIES * DIM;
    // rank (proj->scatter) aliases logits (node_pass->pass3); rank dead first
    unsigned* rank    = (unsigned*)(ws + o);
    float*    logits  = ws + o;               o += N_EDGES;
    u64*      rec     = (u64*)(ws + o);       o += 2 * (size_t)N_EDGES;
    unsigned* keysE   = (unsigned*)rec;       // written in pass3; rec dead by then
    unsigned* keysI   = keysE + N_EDGES;
    unsigned* start   = (unsigned*)(ws + o);  o += N_ENTITIES;
    unsigned* degi    = (unsigned*)(ws + o);  o += N_ENTITIES;        // memset block begins
    float*    sumtail = ws + o;               o += N_ITEMS;
    unsigned* hists   = (unsigned*)(ws + o);  o += 2 * 3 * 256;
    unsigned* counters= (unsigned*)(ws + o);  o += 2;                 // memset block ends
    float2*   nd      = (float2*)(ws + o);    o += 2 * (size_t)N_ENTITIES;
    float*    sumhead = ws + o;               o += N_ENTITIES;
    unsigned* cand    = (unsigned*)(ws + o);  o += 2 * 2 * CAND_CAP;

    // zero: degi + sumtail + hists + counters (contiguous)
    hipMemsetAsync(degi, 0, (size_t)(N_ENTITIES + N_ITEMS + 2 * 3 * 256 + 2) * 4, stream);
    // proj + fused degree-histogram-with-rank
    hipLaunchKernelGGL(proj_kernel, dim3(12500), dim3(256), 0, stream,
                       emb, W, proj, head, degi, rank);
    // exclusive scan -> start (single block)
    hipLaunchKernelGGL(scan_kernel, dim3(1), dim3(1024), 0, stream, degi, start);
    // atomic-free scatter into CSR
    hipLaunchKernelGGL(scatter_kernel, dim3((N_EDGES + 255) / 256), dim3(256), 0, stream,
                       head, tail, etype, rank, start, rec);
    // CSR main pass: one wave per node
    hipLaunchKernelGGL(node_pass, dim3(N_ENTITIES / 4), dim3(256), 0, stream,
                       (const float4*)proj, (const float4*)rel, rec, start, degi,
                       logits, nd, sumhead, sumtail);
    // item keys + item stage-0 hist
    hipLaunchKernelGGL(reduce_items, dim3((N_ITEMS + 255) / 256), dim3(256), 0, stream,
                       sumhead, sumtail, keysI, hists + 3 * 256);
    // scores + noisy keys + edge stage-0 hist
    hipLaunchKernelGGL(edge_pass3, dim3((N_EDGES + 255) / 256), dim3(256), 0, stream,
                       logits, head, (const float2*)nd, noise, out_scores, keysE, hists);
    // shared top-k pipeline
    hipLaunchKernelGGL(hist_stage_kernel, dim3(512, 2), dim3(256), 0, stream,
                       keysE, keysI, hists, 1);
    hipLaunchKernelGGL(hist_stage_kernel, dim3(512, 2), dim3(256), 0, stream,
                       keysE, keysI, hists, 2);
    hipLaunchKernelGGL(collect_kernel, dim3(512, 2), dim3(256), 0, stream,
                       keysE, keysI, hists, counters, cand);
    hipLaunchKernelGGL(final_topk_kernel, dim3(2), dim3(1024), 0, stream,
                       cand, counters, out_topkv, out_topki, out_itemv, out_itemi);
}

// Round 7
// 521.524 us; speedup vs baseline: 1.5917x; 1.5917x over previous
//
#include <hip/hip_runtime.h>

#define N_ENTITIES 200000
#define N_ITEMS    100000
#define DIM        64
#define N_EDGES    1500000
#define K_EDGES    256
#define K_ITEMS    100
// 1 / (2 * sqrt(32))  (mean over 2 heads of per-head 1/sqrt(Dk))
#define SCALE      0.08838834764831845f

#define CAND_CAP   4096
#define NSCANB     ((N_ENTITIES + 255) / 256)   // 782

typedef unsigned long long u64;

// ---- monotonic float<->u32 key (order-preserving, total order) ----
__device__ __forceinline__ unsigned fkey(float x) {
    unsigned u = __float_as_uint(x);
    return (u & 0x80000000u) ? ~u : (u | 0x80000000u);
}
__device__ __forceinline__ float funkey(unsigned k) {
    return (k & 0x80000000u) ? __uint_as_float(k & 0x7fffffffu)
                             : __uint_as_float(~k);
}

// wave-aggregated LDS histogram add: one LDS atomic per distinct bin per wave
__device__ __forceinline__ void lds_hist_add(unsigned* h, unsigned bin, bool valid, int lane) {
    bool need = valid;
    for (;;) {
        unsigned long long mask = __ballot(need);
        if (mask == 0ull) break;
        int leader = __ffsll(mask) - 1;
        unsigned lbin = __shfl(bin, leader, 64);
        bool same = need && (bin == lbin);
        unsigned long long grp = __ballot(same);
        if (lane == leader) atomicAdd(&h[lbin], (unsigned)__popcll(grp));
        need = need && !same;
    }
}

// serial 256-bin select: largest bin b with count(>b) < Keff <= count(>=b).
__device__ __forceinline__ unsigned select_digit(const unsigned* __restrict__ hist,
                                                 unsigned Keff, unsigned* above) {
    unsigned cum = 0;
    int b = 255;
    for (; b > 0; --b) {
        unsigned hb = hist[b];
        if (cum + hb >= Keff) break;
        cum += hb;
    }
    *above = cum;
    return (unsigned)b;
}

// ---- proj = emb @ W_Q, fused with head-degree histogram WITH returned rank
// (the atomic round-trip hides behind the GEMM). 256 thr = (q x c); 16 rows/blk.
__global__ __launch_bounds__(256) void proj_kernel(const float* __restrict__ emb,
                                                   const float* __restrict__ W,
                                                   float* __restrict__ proj,
                                                   const int* __restrict__ head,
                                                   unsigned* __restrict__ degi,
                                                   unsigned* __restrict__ rank) {
    // fused: degree histogram + rank capture (grid 12500*256 = 3.2M >= N_EDGES)
    int e = blockIdx.x * blockDim.x + threadIdx.x;
    if (e < N_EDGES) rank[e] = atomicAdd(&degi[head[e]], 1u);

    __shared__ float part[4][16][64];
    const int t = threadIdx.x;
    const int c = t & 63;
    const int q = __builtin_amdgcn_readfirstlane(t >> 6);

    float Wreg[16];
#pragma unroll
    for (int j = 0; j < 16; ++j) Wreg[j] = W[(q * 16 + j) * 64 + c];

    const int base = blockIdx.x * 16;   // 200000 = 12500 * 16, exact
    const float* erow = emb + (size_t)base * 64 + q * 16;

    float acc[16];
#pragma unroll
    for (int r = 0; r < 16; ++r) acc[r] = 0.f;
#pragma unroll
    for (int r = 0; r < 16; ++r) {
#pragma unroll
        for (int j = 0; j < 16; ++j)
            acc[r] += erow[r * 64 + j] * Wreg[j];
    }
#pragma unroll
    for (int r = 0; r < 16; ++r) part[q][r][c] = acc[r];
    __syncthreads();
#pragma unroll
    for (int it = 0; it < 4; ++it) {
        int oi = t + it * 256;
        int r = oi >> 6, cc = oi & 63;
        float s = part[0][r][cc] + part[1][r][cc] + part[2][r][cc] + part[3][r][cc];
        proj[(size_t)(base + r) * 64 + cc] = s;
    }
}

// ---- hierarchical exclusive scan of degi -> start (3 small kernels) ----
__global__ void scan1_kernel(const unsigned* __restrict__ degi, unsigned* __restrict__ start,
                             unsigned* __restrict__ bsum) {
    __shared__ unsigned s[256];
    int t = threadIdx.x, i = blockIdx.x * 256 + t;
    unsigned v = (i < N_ENTITIES) ? degi[i] : 0u;
    s[t] = v;
    __syncthreads();
    for (int off = 1; off < 256; off <<= 1) {
        unsigned x = s[t];
        unsigned y = (t >= off) ? s[t - off] : 0u;
        __syncthreads();
        s[t] = x + y;
        __syncthreads();
    }
    if (i < N_ENTITIES) start[i] = s[t] - v;   // block-local exclusive
    if (t == 255) bsum[blockIdx.x] = s[t];
}

__global__ void scan2_kernel(const unsigned* __restrict__ bsum, unsigned* __restrict__ bscan) {
    __shared__ unsigned s[1024];
    int t = threadIdx.x;
    unsigned v = (t < NSCANB) ? bsum[t] : 0u;
    s[t] = v;
    __syncthreads();
    for (int off = 1; off < 1024; off <<= 1) {
        unsigned x = s[t];
        unsigned y = (t >= off) ? s[t - off] : 0u;
        __syncthreads();
        s[t] = x + y;
        __syncthreads();
    }
    if (t < NSCANB) bscan[t] = s[t] - v;        // exclusive
}

__global__ void scan3_kernel(unsigned* __restrict__ start, const unsigned* __restrict__ bscan) {
    int i = blockIdx.x * 256 + threadIdx.x;
    if (i < N_ENTITIES) start[i] += bscan[i >> 8];
}

// ---- atomic-free scatter: slot = start[head] + rank ----
// rec = tail(18b)<<27 | rel(6b)<<21 | eid(21b)
__global__ void scatter_kernel(const int* __restrict__ head, const int* __restrict__ tail,
                               const int* __restrict__ etype,
                               const unsigned* __restrict__ rank,
                               const unsigned* __restrict__ start,
                               u64* __restrict__ rec) {
    int i = blockIdx.x * blockDim.x + threadIdx.x;
    if (i >= N_EDGES) return;
    unsigned slot = start[head[i]] + rank[i];
    u64 R = ((u64)(unsigned)tail[i] << 27) | ((u64)(unsigned)(etype[i] - 1) << 21) | (u64)(unsigned)i;
    rec[slot] = R;
}

// ---- CSR main pass: one wave per head node, 4 edges per iteration ----
// denom/deg/sum_head in-register (NO atomics); only sumtail[tail<N_ITEMS] atomic.
__global__ __launch_bounds__(256) void node_pass(const float4* __restrict__ proj4,
                                                 const float4* __restrict__ rel4,
                                                 const u64* __restrict__ rec,
                                                 const unsigned* __restrict__ start,
                                                 const unsigned* __restrict__ degi,
                                                 float* __restrict__ logits,
                                                 float2* __restrict__ nd,
                                                 float* __restrict__ sumhead,
                                                 float* __restrict__ sumtail) {
    int wave = (blockIdx.x * blockDim.x + threadIdx.x) >> 6;   // node id (grid exact)
    int lane = threadIdx.x & 63;
    int slot = lane >> 4, sl = lane & 15;
    unsigned s = start[wave], len = degi[wave];
    float4 ph = proj4[(size_t)wave * 16 + sl];
    float dsum = 0.f, lsum = 0.f;
    for (unsigned k0 = 0; k0 < len; k0 += 4) {
        unsigned k = k0 + slot;
        bool valid = (k < len);
        u64 R = rec[s + (valid ? k : 0u)];
        unsigned t = (unsigned)(R >> 27);
        unsigned r = ((unsigned)(R >> 21)) & 63u;
        unsigned eid = (unsigned)R & 0x1FFFFFu;
        float4 pt = proj4[(size_t)t * 16 + sl];
        float4 pr = rel4[(size_t)r * 16 + sl];
        float v = ph.x * pt.x * pr.x + ph.y * pt.y * pr.y + ph.z * pt.z * pr.z + ph.w * pt.w * pr.w;
        v += __shfl_xor(v, 1, 64);
        v += __shfl_xor(v, 2, 64);
        v += __shfl_xor(v, 4, 64);
        v += __shfl_xor(v, 8, 64);
        if (sl == 0 && valid) {
            float lg = v * SCALE;
            logits[eid] = lg;
            dsum += __expf(lg);
            lsum += lg;
            if (t < N_ITEMS) atomicAdd(&sumtail[t], lg);
        }
    }
    dsum += __shfl_xor(dsum, 16, 64);
    dsum += __shfl_xor(dsum, 32, 64);
    lsum += __shfl_xor(lsum, 16, 64);
    lsum += __shfl_xor(lsum, 32, 64);
    if (lane == 0) {
        nd[wave] = make_float2(dsum, (float)len);
        sumhead[wave] = lsum;
    }
}

// ---- item keys (sumhead + sumtail) + item stage-0 histogram ----
__global__ void reduce_items(const float* __restrict__ a, const float* __restrict__ b,
                             unsigned* __restrict__ keysI, unsigned* __restrict__ histA_I) {
    __shared__ unsigned h[256];
    for (int j = threadIdx.x; j < 256; j += blockDim.x) h[j] = 0;
    __syncthreads();
    int i = blockIdx.x * blockDim.x + threadIdx.x;
    int lane = threadIdx.x & 63;
    unsigned bin = 0;
    bool valid = (i < N_ITEMS);
    if (valid) {
        float s = a[i] + b[i];
        unsigned k = fkey(s);
        keysI[i] = k;
        bin = k >> 24;
    }
    lds_hist_add(h, bin, valid, lane);
    __syncthreads();
    for (int j = threadIdx.x; j < 256; j += blockDim.x) {
        unsigned v = h[j];
        if (v) atomicAdd(&histA_I[j], v);
    }
}

// ---- scores + gumbel keys + edge stage-0 histogram ----
__global__ void edge_pass3(const float* __restrict__ logits, const int* __restrict__ head,
                           const float2* __restrict__ nd, const float* __restrict__ noise_u,
                           float* __restrict__ out_scores, unsigned* __restrict__ keysE,
                           unsigned* __restrict__ histA_E) {
    __shared__ unsigned h[256];
    for (int j = threadIdx.x; j < 256; j += blockDim.x) h[j] = 0;
    __syncthreads();
    int i = blockIdx.x * blockDim.x + threadIdx.x;
    int lane = threadIdx.x & 63;
    unsigned bin = 0;
    bool valid = (i < N_EDGES);
    if (valid) {
        float lg = logits[i];
        float2 dd = nd[head[i]];
        float score = __expf(lg) / dd.x * dd.y;
        out_scores[i] = score;
        float noise = -logf(-logf(noise_u[i]));
        unsigned k = fkey(score + noise);
        keysE[i] = k;
        bin = k >> 24;
    }
    lds_hist_add(h, bin, valid, lane);
    __syncthreads();
    for (int j = threadIdx.x; j < 256; j += blockDim.x) {
        unsigned v = h[j];
        if (v) atomicAdd(&histA_E[j], v);
    }
}

// ---- radix stages 1,2 (grid.y: 0=edges, 1=items); hists [y][stage][256] ----
__global__ void hist_stage_kernel(const unsigned* __restrict__ keysE,
                                  const unsigned* __restrict__ keysI,
                                  unsigned* __restrict__ hists, int stage) {
    __shared__ unsigned h[256];
    for (int j = threadIdx.x; j < 256; j += blockDim.x) h[j] = 0;
    __syncthreads();
    const int y = blockIdx.y;
    const unsigned* keys = y ? keysI : keysE;
    const int n = y ? N_ITEMS : N_EDGES;
    const unsigned K = y ? K_ITEMS : K_EDGES;
    unsigned* H = hists + (size_t)y * 3 * 256;

    unsigned aboveA, prefix;
    unsigned binA = select_digit(H, K, &aboveA);
    if (stage == 1) {
        prefix = binA;
    } else {
        unsigned aboveB;
        unsigned binB = select_digit(H + 256, K - aboveA, &aboveB);
        prefix = (binA << 8) | binB;
    }
    const int shift = 24 - 8 * stage;
    unsigned* out = H + stage * 256;

    const int lane = threadIdx.x & 63;
    const int stride = gridDim.x * blockDim.x;
    for (int idx = blockIdx.x * blockDim.x + threadIdx.x; idx - lane < n; idx += stride) {
        bool valid = (idx < n);
        unsigned bin = 0;
        if (valid) {
            unsigned k = keys[idx];
            if ((k >> (shift + 8)) != prefix) valid = false;
            bin = (k >> shift) & 0xFFu;
        }
        lds_hist_add(h, bin, valid, lane);
    }
    __syncthreads();
    for (int j = threadIdx.x; j < 256; j += blockDim.x) {
        unsigned v = h[j];
        if (v) atomicAdd(&out[j], v);
    }
}

// ---- collect candidates >= 24-bit threshold ----
__global__ void collect_kernel(const unsigned* __restrict__ keysE,
                               const unsigned* __restrict__ keysI,
                               const unsigned* __restrict__ hists,
                               unsigned* __restrict__ counters, unsigned* __restrict__ cand) {
    const int y = blockIdx.y;
    const unsigned* keys = y ? keysI : keysE;
    const int n = y ? N_ITEMS : N_EDGES;
    const unsigned K = y ? K_ITEMS : K_EDGES;
    const unsigned* H = hists + (size_t)y * 3 * 256;
    unsigned aboveA, aboveB, aboveC;
    unsigned binA = select_digit(H, K, &aboveA);
    unsigned binB = select_digit(H + 256, K - aboveA, &aboveB);
    unsigned binC = select_digit(H + 512, K - aboveA - aboveB, &aboveC);
    const unsigned T = ((binA << 16) | (binB << 8) | binC) << 8;
    unsigned* cd = cand + (size_t)y * 2 * CAND_CAP;

    int i = blockIdx.x * blockDim.x + threadIdx.x;
    int stride = gridDim.x * blockDim.x;
    for (; i < n; i += stride) {
        unsigned k = keys[i];
        if (k >= T) {
            unsigned p = atomicAdd(&counters[y], 1u);
            if (p < (unsigned)CAND_CAP) { cd[2 * p] = k; cd[2 * p + 1] = (unsigned)i; }
        }
    }
}

// ---- exact rank among candidates (key desc, index asc); 2 blocks (y) ----
__global__ void final_topk_kernel(const unsigned* __restrict__ cand,
                                  const unsigned* __restrict__ counters,
                                  float* __restrict__ out_topkv, float* __restrict__ out_topki,
                                  float* __restrict__ out_itemv, float* __restrict__ out_itemi) {
    __shared__ unsigned sk[CAND_CAP];
    __shared__ unsigned si[CAND_CAP];
    const int y = blockIdx.x;
    const int K = y ? K_ITEMS : K_EDGES;
    float* outv = y ? out_itemv : out_topkv;
    float* outi = y ? out_itemi : out_topki;
    const unsigned* cd = cand + (size_t)y * 2 * CAND_CAP;
    unsigned m = counters[y];
    if (m > (unsigned)CAND_CAP) m = CAND_CAP;
    for (unsigned i = threadIdx.x; i < m; i += blockDim.x) {
        sk[i] = cd[2 * i];
        si[i] = cd[2 * i + 1];
    }
    __syncthreads();
    for (unsigned i = threadIdx.x; i < m; i += blockDim.x) {
        unsigned ki = sk[i], xi = si[i];
        int r = 0;
        for (unsigned j = 0; j < m; ++j) {
            unsigned kj = sk[j];
            if (kj > ki || (kj == ki && si[j] < xi)) r++;
        }
        if (r < K) {
            outv[r] = funkey(ki);
            outi[r] = (float)xi;
        }
    }
}

extern "C" void kernel_launch(void* const* d_in, const int* in_sizes, int n_in,
                              void* d_out, int out_size, void* d_ws, size_t ws_size,
                              hipStream_t stream) {
    (void)in_sizes; (void)n_in; (void)out_size; (void)ws_size;
    const float* emb    = (const float*)d_in[0];
    const float* W      = (const float*)d_in[1];
    const float* rel    = (const float*)d_in[2];
    const float* noise  = (const float*)d_in[3];
    const int*   eidx   = (const int*)d_in[4];
    const int*   etype  = (const int*)d_in[5];
    const int* head = eidx;
    const int* tail = eidx + N_EDGES;

    float* out        = (float*)d_out;
    float* out_scores = out;
    float* out_topkv  = out + N_EDGES;
    float* out_topki  = out + N_EDGES + K_EDGES;
    float* out_itemv  = out + N_EDGES + 2 * K_EDGES;
    float* out_itemi  = out + N_EDGES + 2 * K_EDGES + K_ITEMS;

    float* ws = (float*)d_ws;
    size_t o = 0;
    float*    proj    = ws + o;               o += (size_t)N_ENTITIES * DIM;
    // rank (proj->scatter) aliases logits (node_pass->pass3); rank dead first
    unsigned* rank    = (unsigned*)(ws + o);
    float*    logits  = ws + o;               o += N_EDGES;
    u64*      rec     = (u64*)(ws + o);       o += 2 * (size_t)N_EDGES;
    unsigned* keysE   = (unsigned*)rec;       // written in pass3; rec dead by then
    unsigned* keysI   = keysE + N_EDGES;
    unsigned* start   = (unsigned*)(ws + o);  o += N_ENTITIES;
    unsigned* degi    = (unsigned*)(ws + o);  o += N_ENTITIES;        // memset block begins
    float*    sumtail = ws + o;               o += N_ITEMS;
    unsigned* hists   = (unsigned*)(ws + o);  o += 2 * 3 * 256;
    unsigned* counters= (unsigned*)(ws + o);  o += 2;                 // memset block ends
    float2*   nd      = (float2*)(ws + o);    o += 2 * (size_t)N_ENTITIES;
    float*    sumhead = ws + o;               o += N_ENTITIES;
    unsigned* bsum    = (unsigned*)(ws + o);  o += 1024;
    unsigned* bscan   = (unsigned*)(ws + o);  o += 1024;
    unsigned* cand    = (unsigned*)(ws + o);  o += 2 * 2 * CAND_CAP;

    // zero: degi + sumtail + hists + counters (contiguous)
    hipMemsetAsync(degi, 0, (size_t)(N_ENTITIES + N_ITEMS + 2 * 3 * 256 + 2) * 4, stream);
    // proj + fused degree-histogram-with-rank
    hipLaunchKernelGGL(proj_kernel, dim3(12500), dim3(256), 0, stream,
                       emb, W, proj, head, degi, rank);
    // hierarchical exclusive scan -> start
    hipLaunchKernelGGL(scan1_kernel, dim3(NSCANB), dim3(256), 0, stream, degi, start, bsum);
    hipLaunchKernelGGL(scan2_kernel, dim3(1), dim3(1024), 0, stream, bsum, bscan);
    hipLaunchKernelGGL(scan3_kernel, dim3(NSCANB), dim3(256), 0, stream, start, bscan);
    // atomic-free scatter into CSR
    hipLaunchKernelGGL(scatter_kernel, dim3((N_EDGES + 255) / 256), dim3(256), 0, stream,
                       head, tail, etype, rank, start, rec);
    // CSR main pass: one wave per node
    hipLaunchKernelGGL(node_pass, dim3(N_ENTITIES / 4), dim3(256), 0, stream,
                       (const float4*)proj, (const float4*)rel, rec, start, degi,
                       logits, nd, sumhead, sumtail);
    // item keys + item stage-0 hist
    hipLaunchKernelGGL(reduce_items, dim3((N_ITEMS + 255) / 256), dim3(256), 0, stream,
                       sumhead, sumtail, keysI, hists + 3 * 256);
    // scores + noisy keys + edge stage-0 hist
    hipLaunchKernelGGL(edge_pass3, dim3((N_EDGES + 255) / 256), dim3(256), 0, stream,
                       logits, head, (const float2*)nd, noise, out_scores, keysE, hists);
    // shared top-k pipeline
    hipLaunchKernelGGL(hist_stage_kernel, dim3(512, 2), dim3(256), 0, stream,
                       keysE, keysI, hists, 1);
    hipLaunchKernelGGL(hist_stage_kernel, dim3(512, 2), dim3(256), 0, stream,
                       keysE, keysI, hists, 2);
    hipLaunchKernelGGL(collect_kernel, dim3(512, 2), dim3(256), 0, stream,
                       keysE, keysI, hists, counters, cand);
    hipLaunchKernelGGL(final_topk_kernel, dim3(2), dim3(1024), 0, stream,
                       cand, counters, out_topkv, out_topki, out_itemv, out_itemi);
}

// Round 8
// 502.305 us; speedup vs baseline: 1.6526x; 1.0383x over previous
//
#include <hip/hip_runtime.h>

#define N_ENTITIES 200000
#define N_ITEMS    100000
#define DIM        64
#define N_EDGES    1500000
#define K_EDGES    256
#define K_ITEMS    100
// 1 / (2 * sqrt(32))  (mean over 2 heads of per-head 1/sqrt(Dk))
#define SCALE      0.08838834764831845f

#define CAND_CAP   4096
#define NSCANB     ((N_ENTITIES + 255) / 256)   // 782

typedef unsigned long long u64;

// ---- monotonic float<->u32 key (order-preserving, total order) ----
__device__ __forceinline__ unsigned fkey(float x) {
    unsigned u = __float_as_uint(x);
    return (u & 0x80000000u) ? ~u : (u | 0x80000000u);
}
__device__ __forceinline__ float funkey(unsigned k) {
    return (k & 0x80000000u) ? __uint_as_float(k & 0x7fffffffu)
                             : __uint_as_float(~k);
}

// wave-aggregated LDS histogram add: one LDS atomic per distinct bin per wave
__device__ __forceinline__ void lds_hist_add(unsigned* h, unsigned bin, bool valid, int lane) {
    bool need = valid;
    for (;;) {
        unsigned long long mask = __ballot(need);
        if (mask == 0ull) break;
        int leader = __ffsll(mask) - 1;
        unsigned lbin = __shfl(bin, leader, 64);
        bool same = need && (bin == lbin);
        unsigned long long grp = __ballot(same);
        if (lane == leader) atomicAdd(&h[lbin], (unsigned)__popcll(grp));
        need = need && !same;
    }
}

// serial 256-bin select: largest bin b with count(>b) < Keff <= count(>=b).
__device__ __forceinline__ unsigned select_digit(const unsigned* __restrict__ hist,
                                                 unsigned Keff, unsigned* above) {
    unsigned cum = 0;
    int b = 255;
    for (; b > 0; --b) {
        unsigned hb = hist[b];
        if (cum + hb >= Keff) break;
        cum += hb;
    }
    *above = cum;
    return (unsigned)b;
}

// ---- proj = emb @ W_Q, fused with head-degree histogram WITH returned rank
// (the atomic round-trip hides behind the GEMM). 256 thr = (q x c); 16 rows/blk.
__global__ __launch_bounds__(256) void proj_kernel(const float* __restrict__ emb,
                                                   const float* __restrict__ W,
                                                   float* __restrict__ proj,
                                                   const int* __restrict__ head,
                                                   unsigned* __restrict__ degi,
                                                   unsigned* __restrict__ rank) {
    // fused: degree histogram + rank capture (grid 12500*256 = 3.2M >= N_EDGES)
    int e = blockIdx.x * blockDim.x + threadIdx.x;
    if (e < N_EDGES) rank[e] = atomicAdd(&degi[head[e]], 1u);

    __shared__ float part[4][16][64];
    const int t = threadIdx.x;
    const int c = t & 63;
    const int q = __builtin_amdgcn_readfirstlane(t >> 6);

    float Wreg[16];
#pragma unroll
    for (int j = 0; j < 16; ++j) Wreg[j] = W[(q * 16 + j) * 64 + c];

    const int base = blockIdx.x * 16;   // 200000 = 12500 * 16, exact
    const float* erow = emb + (size_t)base * 64 + q * 16;

    float acc[16];
#pragma unroll
    for (int r = 0; r < 16; ++r) acc[r] = 0.f;
#pragma unroll
    for (int r = 0; r < 16; ++r) {
#pragma unroll
        for (int j = 0; j < 16; ++j)
            acc[r] += erow[r * 64 + j] * Wreg[j];
    }
#pragma unroll
    for (int r = 0; r < 16; ++r) part[q][r][c] = acc[r];
    __syncthreads();
#pragma unroll
    for (int it = 0; it < 4; ++it) {
        int oi = t + it * 256;
        int r = oi >> 6, cc = oi & 63;
        float s = part[0][r][cc] + part[1][r][cc] + part[2][r][cc] + part[3][r][cc];
        proj[(size_t)(base + r) * 64 + cc] = s;
    }
}

// ---- scan step 1: block-local exclusive scan + block sums ----
__global__ void scan1_kernel(const unsigned* __restrict__ degi, unsigned* __restrict__ start,
                             unsigned* __restrict__ bsum) {
    __shared__ unsigned s[256];
    int t = threadIdx.x, i = blockIdx.x * 256 + t;
    unsigned v = (i < N_ENTITIES) ? degi[i] : 0u;
    s[t] = v;
    __syncthreads();
    for (int off = 1; off < 256; off <<= 1) {
        unsigned x = s[t];
        unsigned y = (t >= off) ? s[t - off] : 0u;
        __syncthreads();
        s[t] = x + y;
        __syncthreads();
    }
    if (i < N_ENTITIES) start[i] = s[t] - v;   // block-local exclusive
    if (t == 255) bsum[blockIdx.x] = s[t];
}

// ---- scan step 2+3 fused: each block sums its bsum prefix and applies ----
__global__ __launch_bounds__(256) void scan23_kernel(const unsigned* __restrict__ bsum,
                                                     unsigned* __restrict__ start) {
    __shared__ unsigned part[4];
    const int b = blockIdx.x;
    const int t = threadIdx.x;
    unsigned s = 0;
    for (int j = t; j < b; j += 256) s += bsum[j];
#pragma unroll
    for (int off = 1; off < 64; off <<= 1) s += __shfl_xor(s, off, 64);
    if ((t & 63) == 0) part[t >> 6] = s;
    __syncthreads();
    unsigned prefix = part[0] + part[1] + part[2] + part[3];
    int i = b * 256 + t;
    if (i < N_ENTITIES) start[i] += prefix;
}

// ---- atomic-free scatter: slot = start[head] + rank ----
// rec = tail(18b)<<27 | rel(6b)<<21 | eid(21b)
__global__ void scatter_kernel(const int* __restrict__ head, const int* __restrict__ tail,
                               const int* __restrict__ etype,
                               const unsigned* __restrict__ rank,
                               const unsigned* __restrict__ start,
                               u64* __restrict__ rec) {
    int i = blockIdx.x * blockDim.x + threadIdx.x;
    if (i >= N_EDGES) return;
    unsigned slot = start[head[i]] + rank[i];
    u64 R = ((u64)(unsigned)tail[i] << 27) | ((u64)(unsigned)(etype[i] - 1) << 21) | (u64)(unsigned)i;
    rec[slot] = R;
}

// ---- CSR main pass: one wave per head node, 8 edges per iteration (2/slot) ----
// denom/deg/sum_head in-register (NO atomics); only sumtail[tail<N_ITEMS] atomic.
__global__ __launch_bounds__(256) void node_pass(const float4* __restrict__ proj4,
                                                 const float4* __restrict__ rel4,
                                                 const u64* __restrict__ rec,
                                                 const unsigned* __restrict__ start,
                                                 const unsigned* __restrict__ degi,
                                                 float* __restrict__ logits,
                                                 float2* __restrict__ nd,
                                                 float* __restrict__ sumhead,
                                                 float* __restrict__ sumtail) {
    int wave = (blockIdx.x * blockDim.x + threadIdx.x) >> 6;   // node id (grid exact)
    int lane = threadIdx.x & 63;
    int slot = lane >> 4, sl = lane & 15;
    unsigned s = start[wave], len = degi[wave];
    float4 ph = proj4[(size_t)wave * 16 + sl];
    float dsum = 0.f, lsum = 0.f;
    for (unsigned k0 = 0; k0 < len; k0 += 8) {
        unsigned ka = k0 + slot, kb = ka + 4;
        bool va = (ka < len), vb = (kb < len);
        u64 Ra = rec[s + (va ? ka : 0u)];
        u64 Rb = rec[s + (vb ? kb : 0u)];
        unsigned ta = (unsigned)(Ra >> 27), ra = ((unsigned)(Ra >> 21)) & 63u;
        unsigned tb = (unsigned)(Rb >> 27), rb = ((unsigned)(Rb >> 21)) & 63u;
        unsigned ea = (unsigned)Ra & 0x1FFFFFu, eb = (unsigned)Rb & 0x1FFFFFu;
        float4 pa = proj4[(size_t)ta * 16 + sl];
        float4 qa = rel4[(size_t)ra * 16 + sl];
        float4 pb = proj4[(size_t)tb * 16 + sl];
        float4 qb = rel4[(size_t)rb * 16 + sl];
        float xa = ph.x * pa.x * qa.x + ph.y * pa.y * qa.y + ph.z * pa.z * qa.z + ph.w * pa.w * qa.w;
        float xb = ph.x * pb.x * qb.x + ph.y * pb.y * qb.y + ph.z * pb.z * qb.z + ph.w * pb.w * qb.w;
        xa += __shfl_xor(xa, 1, 64);  xb += __shfl_xor(xb, 1, 64);
        xa += __shfl_xor(xa, 2, 64);  xb += __shfl_xor(xb, 2, 64);
        xa += __shfl_xor(xa, 4, 64);  xb += __shfl_xor(xb, 4, 64);
        xa += __shfl_xor(xa, 8, 64);  xb += __shfl_xor(xb, 8, 64);
        if (sl == 0) {
            if (va) {
                float lg = xa * SCALE;
                logits[ea] = lg;
                dsum += __expf(lg);
                lsum += lg;
                if (ta < N_ITEMS) atomicAdd(&sumtail[ta], lg);
            }
            if (vb) {
                float lg = xb * SCALE;
                logits[eb] = lg;
                dsum += __expf(lg);
                lsum += lg;
                if (tb < N_ITEMS) atomicAdd(&sumtail[tb], lg);
            }
        }
    }
    dsum += __shfl_xor(dsum, 16, 64);
    dsum += __shfl_xor(dsum, 32, 64);
    lsum += __shfl_xor(lsum, 16, 64);
    lsum += __shfl_xor(lsum, 32, 64);
    if (lane == 0) {
        nd[wave] = make_float2(dsum, (float)len);
        sumhead[wave] = lsum;
    }
}

// ---- scores + gumbel keys + item keys + BOTH stage-0 histograms ----
__global__ void edge_pass3(const float* __restrict__ logits, const int* __restrict__ head,
                           const float2* __restrict__ nd, const float* __restrict__ noise_u,
                           const float* __restrict__ sumhead, const float* __restrict__ sumtail,
                           float* __restrict__ out_scores, unsigned* __restrict__ keysE,
                           unsigned* __restrict__ keysI, unsigned* __restrict__ hists) {
    __shared__ unsigned hE[256];
    __shared__ unsigned hI[256];
    for (int j = threadIdx.x; j < 256; j += blockDim.x) { hE[j] = 0; hI[j] = 0; }
    __syncthreads();
    int i = blockIdx.x * blockDim.x + threadIdx.x;
    int lane = threadIdx.x & 63;

    unsigned bin = 0;
    bool valid = (i < N_EDGES);
    if (valid) {
        float lg = logits[i];
        float2 dd = nd[head[i]];
        float score = __expf(lg) / dd.x * dd.y;
        out_scores[i] = score;
        float noise = -logf(-logf(noise_u[i]));   // library logf: accurate near u->1
        unsigned k = fkey(score + noise);
        keysE[i] = k;
        bin = k >> 24;
    }
    lds_hist_add(hE, bin, valid, lane);

    bin = 0;
    valid = (i < N_ITEMS);
    if (valid) {
        float s = sumhead[i] + sumtail[i];
        unsigned k = fkey(s);
        keysI[i] = k;
        bin = k >> 24;
    }
    lds_hist_add(hI, bin, valid, lane);

    __syncthreads();
    for (int j = threadIdx.x; j < 256; j += blockDim.x) {
        unsigned v = hE[j];
        if (v) atomicAdd(&hists[j], v);
        v = hI[j];
        if (v) atomicAdd(&hists[3 * 256 + j], v);
    }
}

// ---- radix stages 1,2 (grid.y: 0=edges, 1=items); hists [y][stage][256] ----
__global__ void hist_stage_kernel(const unsigned* __restrict__ keysE,
                                  const unsigned* __restrict__ keysI,
                                  unsigned* __restrict__ hists, int stage) {
    __shared__ unsigned h[256];
    for (int j = threadIdx.x; j < 256; j += blockDim.x) h[j] = 0;
    __syncthreads();
    const int y = blockIdx.y;
    const unsigned* keys = y ? keysI : keysE;
    const int n = y ? N_ITEMS : N_EDGES;
    const unsigned K = y ? K_ITEMS : K_EDGES;
    unsigned* H = hists + (size_t)y * 3 * 256;

    unsigned aboveA, prefix;
    unsigned binA = select_digit(H, K, &aboveA);
    if (stage == 1) {
        prefix = binA;
    } else {
        unsigned aboveB;
        unsigned binB = select_digit(H + 256, K - aboveA, &aboveB);
        prefix = (binA << 8) | binB;
    }
    const int shift = 24 - 8 * stage;
    unsigned* out = H + stage * 256;

    const int lane = threadIdx.x & 63;
    const int stride = gridDim.x * blockDim.x;
    for (int idx = blockIdx.x * blockDim.x + threadIdx.x; idx - lane < n; idx += stride) {
        bool valid = (idx < n);
        unsigned bin = 0;
        if (valid) {
            unsigned k = keys[idx];
            if ((k >> (shift + 8)) != prefix) valid = false;
            bin = (k >> shift) & 0xFFu;
        }
        lds_hist_add(h, bin, valid, lane);
    }
    __syncthreads();
    for (int j = threadIdx.x; j < 256; j += blockDim.x) {
        unsigned v = h[j];
        if (v) atomicAdd(&out[j], v);
    }
}

// ---- collect candidates >= 24-bit threshold ----
__global__ void collect_kernel(const unsigned* __restrict__ keysE,
                               const unsigned* __restrict__ keysI,
                               const unsigned* __restrict__ hists,
                               unsigned* __restrict__ counters, unsigned* __restrict__ cand) {
    const int y = blockIdx.y;
    const unsigned* keys = y ? keysI : keysE;
    const int n = y ? N_ITEMS : N_EDGES;
    const unsigned K = y ? K_ITEMS : K_EDGES;
    const unsigned* H = hists + (size_t)y * 3 * 256;
    unsigned aboveA, aboveB, aboveC;
    unsigned binA = select_digit(H, K, &aboveA);
    unsigned binB = select_digit(H + 256, K - aboveA, &aboveB);
    unsigned binC = select_digit(H + 512, K - aboveA - aboveB, &aboveC);
    const unsigned T = ((binA << 16) | (binB << 8) | binC) << 8;
    unsigned* cd = cand + (size_t)y * 2 * CAND_CAP;

    int i = blockIdx.x * blockDim.x + threadIdx.x;
    int stride = gridDim.x * blockDim.x;
    for (; i < n; i += stride) {
        unsigned k = keys[i];
        if (k >= T) {
            unsigned p = atomicAdd(&counters[y], 1u);
            if (p < (unsigned)CAND_CAP) { cd[2 * p] = k; cd[2 * p + 1] = (unsigned)i; }
        }
    }
}

// ---- exact rank among candidates (key desc, index asc); 2 blocks (y) ----
__global__ void final_topk_kernel(const unsigned* __restrict__ cand,
                                  const unsigned* __restrict__ counters,
                                  float* __restrict__ out_topkv, float* __restrict__ out_topki,
                                  float* __restrict__ out_itemv, float* __restrict__ out_itemi) {
    __shared__ unsigned sk[CAND_CAP];
    __shared__ unsigned si[CAND_CAP];
    const int y = blockIdx.x;
    const int K = y ? K_ITEMS : K_EDGES;
    float* outv = y ? out_itemv : out_topkv;
    float* outi = y ? out_itemi : out_topki;
    const unsigned* cd = cand + (size_t)y * 2 * CAND_CAP;
    unsigned m = counters[y];
    if (m > (unsigned)CAND_CAP) m = CAND_CAP;
    for (unsigned i = threadIdx.x; i < m; i += blockDim.x) {
        sk[i] = cd[2 * i];
        si[i] = cd[2 * i + 1];
    }
    __syncthreads();
    for (unsigned i = threadIdx.x; i < m; i += blockDim.x) {
        unsigned ki = sk[i], xi = si[i];
        int r = 0;
        for (unsigned j = 0; j < m; ++j) {
            unsigned kj = sk[j];
            if (kj > ki || (kj == ki && si[j] < xi)) r++;
        }
        if (r < K) {
            outv[r] = funkey(ki);
            outi[r] = (float)xi;
        }
    }
}

extern "C" void kernel_launch(void* const* d_in, const int* in_sizes, int n_in,
                              void* d_out, int out_size, void* d_ws, size_t ws_size,
                              hipStream_t stream) {
    (void)in_sizes; (void)n_in; (void)out_size; (void)ws_size;
    const float* emb    = (const float*)d_in[0];
    const float* W      = (const float*)d_in[1];
    const float* rel    = (const float*)d_in[2];
    const float* noise  = (const float*)d_in[3];
    const int*   eidx   = (const int*)d_in[4];
    const int*   etype  = (const int*)d_in[5];
    const int* head = eidx;
    const int* tail = eidx + N_EDGES;

    float* out        = (float*)d_out;
    float* out_scores = out;
    float* out_topkv  = out + N_EDGES;
    float* out_topki  = out + N_EDGES + K_EDGES;
    float* out_itemv  = out + N_EDGES + 2 * K_EDGES;
    float* out_itemi  = out + N_EDGES + 2 * K_EDGES + K_ITEMS;

    float* ws = (float*)d_ws;
    size_t o = 0;
    float*    proj    = ws + o;               o += (size_t)N_ENTITIES * DIM;
    // rank (proj->scatter) aliases logits (node_pass->pass3); rank dead first
    unsigned* rank    = (unsigned*)(ws + o);
    float*    logits  = ws + o;               o += N_EDGES;
    u64*      rec     = (u64*)(ws + o);       o += 2 * (size_t)N_EDGES;
    unsigned* keysE   = (unsigned*)rec;       // written in pass3; rec dead by then
    unsigned* keysI   = keysE + N_EDGES;
    unsigned* start   = (unsigned*)(ws + o);  o += N_ENTITIES;
    unsigned* degi    = (unsigned*)(ws + o);  o += N_ENTITIES;        // memset block begins
    float*    sumtail = ws + o;               o += N_ITEMS;
    unsigned* hists   = (unsigned*)(ws + o);  o += 2 * 3 * 256;
    unsigned* counters= (unsigned*)(ws + o);  o += 2;                 // memset block ends
    float2*   nd      = (float2*)(ws + o);    o += 2 * (size_t)N_ENTITIES;
    float*    sumhead = ws + o;               o += N_ENTITIES;
    unsigned* bsum    = (unsigned*)(ws + o);  o += 1024;
    unsigned* cand    = (unsigned*)(ws + o);  o += 2 * 2 * CAND_CAP;

    // zero: degi + sumtail + hists + counters (contiguous)
    hipMemsetAsync(degi, 0, (size_t)(N_ENTITIES + N_ITEMS + 2 * 3 * 256 + 2) * 4, stream);
    // proj + fused degree-histogram-with-rank
    hipLaunchKernelGGL(proj_kernel, dim3(12500), dim3(256), 0, stream,
                       emb, W, proj, head, degi, rank);
    // hierarchical exclusive scan -> start (2 kernels)
    hipLaunchKernelGGL(scan1_kernel, dim3(NSCANB), dim3(256), 0, stream, degi, start, bsum);
    hipLaunchKernelGGL(scan23_kernel, dim3(NSCANB), dim3(256), 0, stream, bsum, start);
    // atomic-free scatter into CSR
    hipLaunchKernelGGL(scatter_kernel, dim3((N_EDGES + 255) / 256), dim3(256), 0, stream,
                       head, tail, etype, rank, start, rec);
    // CSR main pass: one wave per node, 8 edges/iter
    hipLaunchKernelGGL(node_pass, dim3(N_ENTITIES / 4), dim3(256), 0, stream,
                       (const float4*)proj, (const float4*)rel, rec, start, degi,
                       logits, nd, sumhead, sumtail);
    // scores + noisy keys + item keys + both stage-0 hists
    hipLaunchKernelGGL(edge_pass3, dim3((N_EDGES + 255) / 256), dim3(256), 0, stream,
                       logits, head, (const float2*)nd, noise, sumhead, sumtail,
                       out_scores, keysE, keysI, hists);
    // shared top-k pipeline
    hipLaunchKernelGGL(hist_stage_kernel, dim3(512, 2), dim3(256), 0, stream,
                       keysE, keysI, hists, 1);
    hipLaunchKernelGGL(hist_stage_kernel, dim3(512, 2), dim3(256), 0, stream,
                       keysE, keysI, hists, 2);
    hipLaunchKernelGGL(collect_kernel, dim3(512, 2), dim3(256), 0, stream,
                       keysE, keysI, hists, counters, cand);
    hipLaunchKernelGGL(final_topk_kernel, dim3(2), dim3(1024), 0, stream,
                       cand, counters, out_topkv, out_topki, out_itemv, out_itemi);
}

// Round 9
// 498.792 us; speedup vs baseline: 1.6642x; 1.0070x over previous
//
#include <hip/hip_runtime.h>

#define N_ENTITIES 200000
#define N_ITEMS    100000
#define DIM        64
#define N_EDGES    1500000
#define K_EDGES    256
#define K_ITEMS    100
// 1 / (2 * sqrt(32))  (mean over 2 heads of per-head 1/sqrt(Dk))
#define SCALE      0.08838834764831845f

#define CAND_CAP   4096
#define NSCANB     ((N_ENTITIES + 255) / 256)   // 782

typedef unsigned long long u64;

// ---- monotonic float<->u32 key (order-preserving, total order) ----
__device__ __forceinline__ unsigned fkey(float x) {
    unsigned u = __float_as_uint(x);
    return (u & 0x80000000u) ? ~u : (u | 0x80000000u);
}
__device__ __forceinline__ float funkey(unsigned k) {
    return (k & 0x80000000u) ? __uint_as_float(k & 0x7fffffffu)
                             : __uint_as_float(~k);
}

// wave-aggregated LDS histogram add: one LDS atomic per distinct bin per wave
__device__ __forceinline__ void lds_hist_add(unsigned* h, unsigned bin, bool valid, int lane) {
    bool need = valid;
    for (;;) {
        unsigned long long mask = __ballot(need);
        if (mask == 0ull) break;
        int leader = __ffsll(mask) - 1;
        unsigned lbin = __shfl(bin, leader, 64);
        bool same = need && (bin == lbin);
        unsigned long long grp = __ballot(same);
        if (lane == leader) atomicAdd(&h[lbin], (unsigned)__popcll(grp));
        need = need && !same;
    }
}

// serial 256-bin select: largest bin b with count(>b) < Keff <= count(>=b).
__device__ __forceinline__ unsigned select_digit(const unsigned* __restrict__ hist,
                                                 unsigned Keff, unsigned* above) {
    unsigned cum = 0;
    int b = 255;
    for (; b > 0; --b) {
        unsigned hb = hist[b];
        if (cum + hb >= Keff) break;
        cum += hb;
    }
    *above = cum;
    return (unsigned)b;
}

// ---- proj = emb @ W_Q, fused with head-degree histogram WITH returned rank.
// Atomic issued FIRST, rank stored LAST: the GEMM hides the atomic round trip.
__global__ __launch_bounds__(256) void proj_kernel(const float* __restrict__ emb,
                                                   const float* __restrict__ W,
                                                   float* __restrict__ proj,
                                                   const int* __restrict__ head,
                                                   unsigned* __restrict__ degi,
                                                   unsigned* __restrict__ rank) {
    // fused: degree histogram + rank capture (grid 12500*256 = 3.2M >= N_EDGES)
    int e = blockIdx.x * blockDim.x + threadIdx.x;
    unsigned rk = 0;
    bool haveEdge = (e < N_EDGES);
    if (haveEdge) rk = atomicAdd(&degi[head[e]], 1u);

    __shared__ float part[4][16][64];
    const int t = threadIdx.x;
    const int c = t & 63;
    const int q = __builtin_amdgcn_readfirstlane(t >> 6);

    float Wreg[16];
#pragma unroll
    for (int j = 0; j < 16; ++j) Wreg[j] = W[(q * 16 + j) * 64 + c];

    const int base = blockIdx.x * 16;   // 200000 = 12500 * 16, exact
    const float* erow = emb + (size_t)base * 64 + q * 16;

    float acc[16];
#pragma unroll
    for (int r = 0; r < 16; ++r) acc[r] = 0.f;
#pragma unroll
    for (int r = 0; r < 16; ++r) {
#pragma unroll
        for (int j = 0; j < 16; ++j)
            acc[r] += erow[r * 64 + j] * Wreg[j];
    }
#pragma unroll
    for (int r = 0; r < 16; ++r) part[q][r][c] = acc[r];
    __syncthreads();
#pragma unroll
    for (int it = 0; it < 4; ++it) {
        int oi = t + it * 256;
        int r = oi >> 6, cc = oi & 63;
        float s = part[0][r][cc] + part[1][r][cc] + part[2][r][cc] + part[3][r][cc];
        proj[(size_t)(base + r) * 64 + cc] = s;
    }
    // sunk store: atomic return consumed only here
    if (haveEdge) rank[e] = rk;
}

// ---- scan step 1: block-local exclusive scan + block sums ----
__global__ void scan1_kernel(const unsigned* __restrict__ degi, unsigned* __restrict__ start,
                             unsigned* __restrict__ bsum) {
    __shared__ unsigned s[256];
    int t = threadIdx.x, i = blockIdx.x * 256 + t;
    unsigned v = (i < N_ENTITIES) ? degi[i] : 0u;
    s[t] = v;
    __syncthreads();
    for (int off = 1; off < 256; off <<= 1) {
        unsigned x = s[t];
        unsigned y = (t >= off) ? s[t - off] : 0u;
        __syncthreads();
        s[t] = x + y;
        __syncthreads();
    }
    if (i < N_ENTITIES) start[i] = s[t] - v;   // block-local exclusive
    if (t == 255) bsum[blockIdx.x] = s[t];
}

// ---- scan step 2+3 fused: each block sums its bsum prefix and applies ----
__global__ __launch_bounds__(256) void scan23_kernel(const unsigned* __restrict__ bsum,
                                                     unsigned* __restrict__ start) {
    __shared__ unsigned part[4];
    const int b = blockIdx.x;
    const int t = threadIdx.x;
    unsigned s = 0;
    for (int j = t; j < b; j += 256) s += bsum[j];
#pragma unroll
    for (int off = 1; off < 64; off <<= 1) s += __shfl_xor(s, off, 64);
    if ((t & 63) == 0) part[t >> 6] = s;
    __syncthreads();
    unsigned prefix = part[0] + part[1] + part[2] + part[3];
    int i = b * 256 + t;
    if (i < N_ENTITIES) start[i] += prefix;
}

// ---- atomic-free scatter: slot = start[head] + rank ----
// rec = tail(18b)<<27 | rel(6b)<<21 | eid(21b)
__global__ void scatter_kernel(const int* __restrict__ head, const int* __restrict__ tail,
                               const int* __restrict__ etype,
                               const unsigned* __restrict__ rank,
                               const unsigned* __restrict__ start,
                               u64* __restrict__ rec) {
    int i = blockIdx.x * blockDim.x + threadIdx.x;
    if (i >= N_EDGES) return;
    unsigned slot = start[head[i]] + rank[i];
    u64 R = ((u64)(unsigned)tail[i] << 27) | ((u64)(unsigned)(etype[i] - 1) << 21) | (u64)(unsigned)i;
    rec[slot] = R;
}

// ---- CSR main pass: one wave per head node, 8 edges per iteration (2/slot) ----
// denom/deg/sum_head in-register (NO atomics); sumtail atomics go to the
// per-XCD replica (rep = XCC_ID & repMask) -> lines stay in the local L2,
// no cross-XCD bouncing through HBM.
__global__ __launch_bounds__(256) void node_pass(const float4* __restrict__ proj4,
                                                 const float4* __restrict__ rel4,
                                                 const u64* __restrict__ rec,
                                                 const unsigned* __restrict__ start,
                                                 const unsigned* __restrict__ degi,
                                                 float* __restrict__ logits,
                                                 float2* __restrict__ nd,
                                                 float* __restrict__ sumhead,
                                                 float* __restrict__ sumtailR,
                                                 int repMask) {
    unsigned xcd;
    asm volatile("s_getreg_b32 %0, hwreg(HW_REG_XCC_ID)" : "=s"(xcd));
    float* st = sumtailR + (size_t)(xcd & (unsigned)repMask) * N_ITEMS;

    int wave = (blockIdx.x * blockDim.x + threadIdx.x) >> 6;   // node id (grid exact)
    int lane = threadIdx.x & 63;
    int slot = lane >> 4, sl = lane & 15;
    unsigned s = start[wave], len = degi[wave];
    float4 ph = proj4[(size_t)wave * 16 + sl];
    float dsum = 0.f, lsum = 0.f;
    for (unsigned k0 = 0; k0 < len; k0 += 8) {
        unsigned ka = k0 + slot, kb = ka + 4;
        bool va = (ka < len), vb = (kb < len);
        u64 Ra = rec[s + (va ? ka : 0u)];
        u64 Rb = rec[s + (vb ? kb : 0u)];
        unsigned ta = (unsigned)(Ra >> 27), ra = ((unsigned)(Ra >> 21)) & 63u;
        unsigned tb = (unsigned)(Rb >> 27), rb = ((unsigned)(Rb >> 21)) & 63u;
        unsigned ea = (unsigned)Ra & 0x1FFFFFu, eb = (unsigned)Rb & 0x1FFFFFu;
        float4 pa = proj4[(size_t)ta * 16 + sl];
        float4 qa = rel4[(size_t)ra * 16 + sl];
        float4 pb = proj4[(size_t)tb * 16 + sl];
        float4 qb = rel4[(size_t)rb * 16 + sl];
        float xa = ph.x * pa.x * qa.x + ph.y * pa.y * qa.y + ph.z * pa.z * qa.z + ph.w * pa.w * qa.w;
        float xb = ph.x * pb.x * qb.x + ph.y * pb.y * qb.y + ph.z * pb.z * qb.z + ph.w * pb.w * qb.w;
        xa += __shfl_xor(xa, 1, 64);  xb += __shfl_xor(xb, 1, 64);
        xa += __shfl_xor(xa, 2, 64);  xb += __shfl_xor(xb, 2, 64);
        xa += __shfl_xor(xa, 4, 64);  xb += __shfl_xor(xb, 4, 64);
        xa += __shfl_xor(xa, 8, 64);  xb += __shfl_xor(xb, 8, 64);
        if (sl == 0) {
            if (va) {
                float lg = xa * SCALE;
                logits[ea] = lg;
                dsum += __expf(lg);
                lsum += lg;
                if (ta < N_ITEMS) atomicAdd(&st[ta], lg);
            }
            if (vb) {
                float lg = xb * SCALE;
                logits[eb] = lg;
                dsum += __expf(lg);
                lsum += lg;
                if (tb < N_ITEMS) atomicAdd(&st[tb], lg);
            }
        }
    }
    dsum += __shfl_xor(dsum, 16, 64);
    dsum += __shfl_xor(dsum, 32, 64);
    lsum += __shfl_xor(lsum, 16, 64);
    lsum += __shfl_xor(lsum, 32, 64);
    if (lane == 0) {
        nd[wave] = make_float2(dsum, (float)len);
        sumhead[wave] = lsum;
    }
}

// ---- scores + gumbel keys + item keys (replica fold) + BOTH stage-0 hists ----
__global__ void edge_pass3(const float* __restrict__ logits, const int* __restrict__ head,
                           const float2* __restrict__ nd, const float* __restrict__ noise_u,
                           const float* __restrict__ sumhead, const float* __restrict__ sumtailR,
                           int R,
                           float* __restrict__ out_scores, unsigned* __restrict__ keysE,
                           unsigned* __restrict__ keysI, unsigned* __restrict__ hists) {
    __shared__ unsigned hE[256];
    __shared__ unsigned hI[256];
    for (int j = threadIdx.x; j < 256; j += blockDim.x) { hE[j] = 0; hI[j] = 0; }
    __syncthreads();
    int i = blockIdx.x * blockDim.x + threadIdx.x;
    int lane = threadIdx.x & 63;

    unsigned bin = 0;
    bool valid = (i < N_EDGES);
    if (valid) {
        float lg = logits[i];
        float2 dd = nd[head[i]];
        float score = __expf(lg) / dd.x * dd.y;
        out_scores[i] = score;
        float noise = -logf(-logf(noise_u[i]));   // library logf: accurate near u->1
        unsigned k = fkey(score + noise);
        keysE[i] = k;
        bin = k >> 24;
    }
    lds_hist_add(hE, bin, valid, lane);

    bin = 0;
    valid = (i < N_ITEMS);
    if (valid) {
        float s = sumhead[i];
        for (int r = 0; r < R; ++r) s += sumtailR[(size_t)r * N_ITEMS + i];
        unsigned k = fkey(s);
        keysI[i] = k;
        bin = k >> 24;
    }
    lds_hist_add(hI, bin, valid, lane);

    __syncthreads();
    for (int j = threadIdx.x; j < 256; j += blockDim.x) {
        unsigned v = hE[j];
        if (v) atomicAdd(&hists[j], v);
        v = hI[j];
        if (v) atomicAdd(&hists[3 * 256 + j], v);
    }
}

// ---- radix stages 1,2 (grid.y: 0=edges, 1=items); hists [y][stage][256] ----
__global__ void hist_stage_kernel(const unsigned* __restrict__ keysE,
                                  const unsigned* __restrict__ keysI,
                                  unsigned* __restrict__ hists, int stage) {
    __shared__ unsigned h[256];
    for (int j = threadIdx.x; j < 256; j += blockDim.x) h[j] = 0;
    __syncthreads();
    const int y = blockIdx.y;
    const unsigned* keys = y ? keysI : keysE;
    const int n = y ? N_ITEMS : N_EDGES;
    const unsigned K = y ? K_ITEMS : K_EDGES;
    unsigned* H = hists + (size_t)y * 3 * 256;

    unsigned aboveA, prefix;
    unsigned binA = select_digit(H, K, &aboveA);
    if (stage == 1) {
        prefix = binA;
    } else {
        unsigned aboveB;
        unsigned binB = select_digit(H + 256, K - aboveA, &aboveB);
        prefix = (binA << 8) | binB;
    }
    const int shift = 24 - 8 * stage;
    unsigned* out = H + stage * 256;

    const int lane = threadIdx.x & 63;
    const int stride = gridDim.x * blockDim.x;
    for (int idx = blockIdx.x * blockDim.x + threadIdx.x; idx - lane < n; idx += stride) {
        bool valid = (idx < n);
        unsigned bin = 0;
        if (valid) {
            unsigned k = keys[idx];
            if ((k >> (shift + 8)) != prefix) valid = false;
            bin = (k >> shift) & 0xFFu;
        }
        lds_hist_add(h, bin, valid, lane);
    }
    __syncthreads();
    for (int j = threadIdx.x; j < 256; j += blockDim.x) {
        unsigned v = h[j];
        if (v) atomicAdd(&out[j], v);
    }
}

// ---- collect candidates >= 24-bit threshold ----
__global__ void collect_kernel(const unsigned* __restrict__ keysE,
                               const unsigned* __restrict__ keysI,
                               const unsigned* __restrict__ hists,
                               unsigned* __restrict__ counters, unsigned* __restrict__ cand) {
    const int y = blockIdx.y;
    const unsigned* keys = y ? keysI : keysE;
    const int n = y ? N_ITEMS : N_EDGES;
    const unsigned K = y ? K_ITEMS : K_EDGES;
    const unsigned* H = hists + (size_t)y * 3 * 256;
    unsigned aboveA, aboveB, aboveC;
    unsigned binA = select_digit(H, K, &aboveA);
    unsigned binB = select_digit(H + 256, K - aboveA, &aboveB);
    unsigned binC = select_digit(H + 512, K - aboveA - aboveB, &aboveC);
    const unsigned T = ((binA << 16) | (binB << 8) | binC) << 8;
    unsigned* cd = cand + (size_t)y * 2 * CAND_CAP;

    int i = blockIdx.x * blockDim.x + threadIdx.x;
    int stride = gridDim.x * blockDim.x;
    for (; i < n; i += stride) {
        unsigned k = keys[i];
        if (k >= T) {
            unsigned p = atomicAdd(&counters[y], 1u);
            if (p < (unsigned)CAND_CAP) { cd[2 * p] = k; cd[2 * p + 1] = (unsigned)i; }
        }
    }
}

// ---- exact rank among candidates (key desc, index asc); 2 blocks (y) ----
__global__ void final_topk_kernel(const unsigned* __restrict__ cand,
                                  const unsigned* __restrict__ counters,
                                  float* __restrict__ out_topkv, float* __restrict__ out_topki,
                                  float* __restrict__ out_itemv, float* __restrict__ out_itemi) {
    __shared__ unsigned sk[CAND_CAP];
    __shared__ unsigned si[CAND_CAP];
    const int y = blockIdx.x;
    const int K = y ? K_ITEMS : K_EDGES;
    float* outv = y ? out_itemv : out_topkv;
    float* outi = y ? out_itemi : out_topki;
    const unsigned* cd = cand + (size_t)y * 2 * CAND_CAP;
    unsigned m = counters[y];
    if (m > (unsigned)CAND_CAP) m = CAND_CAP;
    for (unsigned i = threadIdx.x; i < m; i += blockDim.x) {
        sk[i] = cd[2 * i];
        si[i] = cd[2 * i + 1];
    }
    __syncthreads();
    for (unsigned i = threadIdx.x; i < m; i += blockDim.x) {
        unsigned ki = sk[i], xi = si[i];
        int r = 0;
        for (unsigned j = 0; j < m; ++j) {
            unsigned kj = sk[j];
            if (kj > ki || (kj == ki && si[j] < xi)) r++;
        }
        if (r < K) {
            outv[r] = funkey(ki);
            outi[r] = (float)xi;
        }
    }
}

extern "C" void kernel_launch(void* const* d_in, const int* in_sizes, int n_in,
                              void* d_out, int out_size, void* d_ws, size_t ws_size,
                              hipStream_t stream) {
    (void)in_sizes; (void)n_in; (void)out_size;
    const float* emb    = (const float*)d_in[0];
    const float* W      = (const float*)d_in[1];
    const float* rel    = (const float*)d_in[2];
    const float* noise  = (const float*)d_in[3];
    const int*   eidx   = (const int*)d_in[4];
    const int*   etype  = (const int*)d_in[5];
    const int* head = eidx;
    const int* tail = eidx + N_EDGES;

    float* out        = (float*)d_out;
    float* out_scores = out;
    float* out_topkv  = out + N_EDGES;
    float* out_topki  = out + N_EDGES + K_EDGES;
    float* out_itemv  = out + N_EDGES + 2 * K_EDGES;
    float* out_itemi  = out + N_EDGES + 2 * K_EDGES + K_ITEMS;

    // adaptive replica count: largest R in {8,4,2,1} whose layout fits ws
    auto layout_floats = [](int R) -> size_t {
        return (size_t)N_ENTITIES * DIM + N_EDGES + 2 * (size_t)N_EDGES
             + N_ENTITIES + N_ENTITIES + (size_t)R * N_ITEMS
             + 2 * 3 * 256 + 2 + 2 * (size_t)N_ENTITIES + N_ENTITIES
             + 1024 + 2 * 2 * CAND_CAP;
    };
    int R = 8;
    while (R > 1 && ws_size < layout_floats(R) * 4) R >>= 1;

    float* ws = (float*)d_ws;
    size_t o = 0;
    float*    proj    = ws + o;               o += (size_t)N_ENTITIES * DIM;
    // rank (proj->scatter) aliases logits (node_pass->pass3); rank dead first
    unsigned* rank    = (unsigned*)(ws + o);
    float*    logits  = ws + o;               o += N_EDGES;
    u64*      rec     = (u64*)(ws + o);       o += 2 * (size_t)N_EDGES;
    unsigned* keysE   = (unsigned*)rec;       // written in pass3; rec dead by then
    unsigned* keysI   = keysE + N_EDGES;
    unsigned* start   = (unsigned*)(ws + o);  o += N_ENTITIES;
    unsigned* degi    = (unsigned*)(ws + o);  o += N_ENTITIES;        // memset block begins
    float*    sumtailR= ws + o;               o += (size_t)R * N_ITEMS;
    unsigned* hists   = (unsigned*)(ws + o);  o += 2 * 3 * 256;
    unsigned* counters= (unsigned*)(ws + o);  o += 2;                 // memset block ends
    float2*   nd      = (float2*)(ws + o);    o += 2 * (size_t)N_ENTITIES;
    float*    sumhead = ws + o;               o += N_ENTITIES;
    unsigned* bsum    = (unsigned*)(ws + o);  o += 1024;
    unsigned* cand    = (unsigned*)(ws + o);  o += 2 * 2 * CAND_CAP;

    // zero: degi + sumtailR + hists + counters (contiguous)
    hipMemsetAsync(degi, 0,
                   ((size_t)N_ENTITIES + (size_t)R * N_ITEMS + 2 * 3 * 256 + 2) * 4, stream);
    // proj + fused degree-histogram-with-rank (store sunk past the GEMM)
    hipLaunchKernelGGL(proj_kernel, dim3(12500), dim3(256), 0, stream,
                       emb, W, proj, head, degi, rank);
    // hierarchical exclusive scan -> start (2 kernels)
    hipLaunchKernelGGL(scan1_kernel, dim3(NSCANB), dim3(256), 0, stream, degi, start, bsum);
    hipLaunchKernelGGL(scan23_kernel, dim3(NSCANB), dim3(256), 0, stream, bsum, start);
    // atomic-free scatter into CSR
    hipLaunchKernelGGL(scatter_kernel, dim3((N_EDGES + 255) / 256), dim3(256), 0, stream,
                       head, tail, etype, rank, start, rec);
    // CSR main pass: one wave per node, 8 edges/iter, XCD-replica sumtail
    hipLaunchKernelGGL(node_pass, dim3(N_ENTITIES / 4), dim3(256), 0, stream,
                       (const float4*)proj, (const float4*)rel, rec, start, degi,
                       logits, nd, sumhead, sumtailR, R - 1);
    // scores + noisy keys + item keys (fold replicas) + both stage-0 hists
    hipLaunchKernelGGL(edge_pass3, dim3((N_EDGES + 255) / 256), dim3(256), 0, stream,
                       logits, head, (const float2*)nd, noise, sumhead, sumtailR, R,
                       out_scores, keysE, keysI, hists);
    // shared top-k pipeline
    hipLaunchKernelGGL(hist_stage_kernel, dim3(512, 2), dim3(256), 0, stream,
                       keysE, keysI, hists, 1);
    hipLaunchKernelGGL(hist_stage_kernel, dim3(512, 2), dim3(256), 0, stream,
                       keysE, keysI, hists, 2);
    hipLaunchKernelGGL(collect_kernel, dim3(512, 2), dim3(256), 0, stream,
                       keysE, keysI, hists, counters, cand);
    hipLaunchKernelGGL(final_topk_kernel, dim3(2), dim3(1024), 0, stream,
                       cand, counters, out_topkv, out_topki, out_itemv, out_itemi);
}